// Round 3
// baseline (276.532 us; speedup 1.0000x reference)
//
#include <hip/hip_runtime.h>

#define K_CODES 1024
#define DIM     256
#define NROWS   65536      // 64*32*32
#define THREADS 128        // 2 waves per block
#define ROWS_PER_WAVE 32
#define ROWS_PER_BLOCK 64
#define NBLOCKS (NROWS / ROWS_PER_BLOCK)   // 1024

typedef __attribute__((ext_vector_type(8))) short short8;
typedef __attribute__((ext_vector_type(4))) float f32x4;

__device__ __forceinline__ unsigned short f2bf(float f) {
    unsigned int u = __float_as_uint(f);
    u += 0x7fffu + ((u >> 16) & 1u);          // round-to-nearest-even
    return (unsigned short)(u >> 16);
}

// ---- kernel 0: emb f32 -> bf16, row norms, zero loss accumulator ----
__global__ void k_prep(const float* __restrict__ emb,
                       unsigned short* __restrict__ embb,
                       float* __restrict__ normE,
                       float* __restrict__ lossAcc) {
    const int k = blockIdx.x * 4 + (threadIdx.x >> 6);   // code row
    const int l = threadIdx.x & 63;
    float4 v = reinterpret_cast<const float4*>(emb)[k * 64 + l];
    ushort4 b;
    b.x = f2bf(v.x); b.y = f2bf(v.y); b.z = f2bf(v.z); b.w = f2bf(v.w);
    reinterpret_cast<ushort4*>(embb)[k * 64 + l] = b;
    float s = v.x*v.x + v.y*v.y + v.z*v.z + v.w*v.w;
    #pragma unroll
    for (int m = 1; m < 64; m <<= 1) s += __shfl_xor(s, m, 64);
    if (l == 0) normE[k] = s;
    if (k == 0 && l == 0) *lossAcc = 0.f;
}

// ---- kernel 1: barrier-free, LDS-free MFMA scan ----
// Each wave owns 32 z-rows (two 16-row MFMA tiles), scans all 1024 codes in
// 64 chunks of 16. B-fragments load straight from global (L1/L2-resident
// codebook); the two row-tiles share every B-fragment. Per-lane running
// argmin as tagged floats (low 10 mantissa bits = 1023-code), one v_max each.
__launch_bounds__(THREADS, 4)
__global__ void k_main(const float* __restrict__ z,
                       const unsigned short* __restrict__ embb,
                       const float* __restrict__ normE,
                       const float* __restrict__ emb,
                       float* __restrict__ out,
                       float* __restrict__ lossAcc) {
    const int tid   = threadIdx.x;
    const int lane  = tid & 63;
    const int w     = tid >> 6;           // 0..1
    const int col16 = lane & 15;
    const int q16   = lane >> 4;          // 0..3
    const long grow0 = (long)blockIdx.x * ROWS_PER_BLOCK + w * ROWS_PER_WAVE;

    // ---- A fragments (bf16, registers) + exact f32 row norms ----
    // 16x16x32 A layout: lane holds A[row=l&15][k=(l>>4)*8+j]
    short8 af[2][8];
    float  zn[2];
    #pragma unroll
    for (int t = 0; t < 2; ++t) {
        const float* zr = z + (grow0 + t * 16 + col16) * DIM + q16 * 8;
        float s = 0.f;
        #pragma unroll
        for (int m = 0; m < 8; ++m) {
            float4 a = *reinterpret_cast<const float4*>(zr + m * 32);
            float4 b = *reinterpret_cast<const float4*>(zr + m * 32 + 4);
            s += a.x*a.x + a.y*a.y + a.z*a.z + a.w*a.w
               + b.x*b.x + b.y*b.y + b.z*b.z + b.w*b.w;
            short8 sv;
            sv[0]=(short)f2bf(a.x); sv[1]=(short)f2bf(a.y); sv[2]=(short)f2bf(a.z); sv[3]=(short)f2bf(a.w);
            sv[4]=(short)f2bf(b.x); sv[5]=(short)f2bf(b.y); sv[6]=(short)f2bf(b.z); sv[7]=(short)f2bf(b.w);
            af[t][m] = sv;
        }
        s += __shfl_xor(s, 16, 64);       // combine the 4 k-quarter lanes
        s += __shfl_xor(s, 32, 64);
        zn[t] = s;                        // norm of row (t*16 + col16)
    }

    // ---- main scan: 64 chunks x 16 codes, no barriers, no LDS ----
    float kb0[4], kb1[4];
    #pragma unroll
    for (int r = 0; r < 4; ++r) { kb0[r] = -1e30f; kb1[r] = -1e30f; }

    const char* ebase = reinterpret_cast<const char*>(embb)
                        + (size_t)col16 * 512 + (size_t)q16 * 16;

    for (int c = 0; c < 64; ++c) {
        const int mycode = c * 16 + col16;
        const float hne = -0.5f * normE[mycode];
        f32x4 a0 = {hne, hne, hne, hne};      // acc starts at -||e||^2/2
        f32x4 a1 = {hne, hne, hne, hne};
        const char* bp = ebase + (size_t)c * (16 * 512);
        #pragma unroll
        for (int m = 0; m < 8; ++m) {
            short8 bf = *reinterpret_cast<const short8*>(bp + m * 64);
            a0 = __builtin_amdgcn_mfma_f32_16x16x32_bf16(af[0][m], bf, a0, 0, 0, 0);
            a1 = __builtin_amdgcn_mfma_f32_16x16x32_bf16(af[1][m], bf, a1, 0, 0, 0);
        }
        // maximize (z.e - ||e||^2/2); tag low 10 mantissa bits with 1023-code
        const unsigned tag = 1023u - (unsigned)mycode;
        #pragma unroll
        for (int r = 0; r < 4; ++r) {
            kb0[r] = fmaxf(kb0[r], __uint_as_float((__float_as_uint(a0[r]) & 0xFFFFFC00u) | tag));
            kb1[r] = fmaxf(kb1[r], __uint_as_float((__float_as_uint(a1[r]) & 0xFFFFFC00u) | tag));
        }
    }

    // ---- cross-lane max over the 16 col-lanes (stays within 16-group) ----
    #pragma unroll
    for (int r = 0; r < 4; ++r) {
        #pragma unroll
        for (int m = 1; m < 16; m <<= 1) {
            kb0[r] = fmaxf(kb0[r], __shfl_xor(kb0[r], m, 64));
            kb1[r] = fmaxf(kb1[r], __shfl_xor(kb1[r], m, 64));
        }
    }
    // now every lane holds, for its q-group, the best key of row q*4+r (per tile)

    // ---- epilogue: per-row gather (1 KB coalesced per instruction) + loss ----
    float lp = 0.f;
    #pragma unroll
    for (int rr = 0; rr < 32; ++rr) {
        const int t = rr >> 4, r16 = rr & 15;
        const int q = r16 >> 2, rsub = r16 & 3;
        float kv = __shfl((t == 0) ? kb0[rsub] : kb1[rsub], q * 16, 64);
        const unsigned ku = __float_as_uint(kv);
        const int   code  = 1023 - (int)(ku & 1023u);
        const float score = __uint_as_float(ku & 0xFFFFFC00u);   // dot - ||e||^2/2
        float4 v = *reinterpret_cast<const float4*>(emb + (size_t)code * DIM + lane * 4);
        *reinterpret_cast<float4*>(out + (size_t)(grow0 + rr) * DIM + lane * 4) = v;
        float zr = __shfl(zn[t], r16, 64);                        // ||z_row||^2
        lp += zr - 2.f * score;                                   // = ||z - e||^2
    }
    if (lane == 0) atomicAdd(lossAcc, lp);
}

// ---- kernel 2: finalize losses ----
__global__ void k_loss(const float* __restrict__ lossAcc, float* __restrict__ out2) {
    float loss = 0.5f * lossAcc[0] * (1.f / 16777216.f);   // 0.5 * mean over N*D
    out2[0] = loss;
    out2[1] = loss;
}

extern "C" void kernel_launch(void* const* d_in, const int* in_sizes, int n_in,
                              void* d_out, int out_size, void* d_ws, size_t ws_size,
                              hipStream_t stream) {
    const float* z   = (const float*)d_in[0];
    const float* emb = (const float*)d_in[1];
    float* out = (float*)d_out;
    char*  ws  = (char*)d_ws;
    float* lossAcc       = (float*)ws;                         // 4 B
    float* normE         = (float*)(ws + 256);                 // 4 KB
    unsigned short* embb = (unsigned short*)(ws + 256 + 4096); // 512 KB

    k_prep<<<K_CODES / 4, 256, 0, stream>>>(emb, embb, normE, lossAcc);
    k_main<<<NBLOCKS, THREADS, 0, stream>>>(z, embb, normE, emb, out, lossAcc);
    k_loss<<<1, 1, 0, stream>>>(lossAcc, out + (long)NROWS * DIM);
}

// Round 4
// 199.163 us; speedup vs baseline: 1.3885x; 1.3885x over previous
//
#include <hip/hip_runtime.h>

#define K_CODES 1024
#define DIM     256
#define NROWS   65536      // 64*32*32
#define THREADS 256        // 4 waves per block
#define ROWS_PER_WAVE 32
#define ROWS_PER_BLOCK 128
#define NBLOCKS (NROWS / ROWS_PER_BLOCK)   // 512

typedef __attribute__((ext_vector_type(8))) short short8;
typedef __attribute__((ext_vector_type(4))) float f32x4;

__device__ __forceinline__ unsigned short f2bf(float f) {
    unsigned int u = __float_as_uint(f);
    u += 0x7fffu + ((u >> 16) & 1u);          // round-to-nearest-even
    return (unsigned short)(u >> 16);
}

// ---- kernel 0: pack codebook into MFMA-B-fragment order + hne table ----
// embb2 record (c,m) lane l (16B): e[c*16 + (l&15)][m*32 + (l>>4)*8 + j], j=0..7
// -> k_main B-load is 64 lanes x 16B fully contiguous (1 KB/instr).
__global__ void k_prep(const float* __restrict__ emb,
                       unsigned short* __restrict__ embb2,
                       float* __restrict__ hneT,
                       float* __restrict__ lossAcc) {
    __shared__ float snormw[8][16];
    const int c   = blockIdx.x;        // chunk of 16 codes
    const int tid = threadIdx.x;
    const int m   = tid >> 6;          // fragment 0..7 (one wave each)
    const int l   = tid & 63;
    const int r   = l & 15;
    const int q   = l >> 4;

    const float* src = emb + (size_t)(c * 16 + r) * DIM + m * 32 + q * 8;
    float4 a = *reinterpret_cast<const float4*>(src);
    float4 b = *reinterpret_cast<const float4*>(src + 4);
    float s = a.x*a.x + a.y*a.y + a.z*a.z + a.w*a.w
            + b.x*b.x + b.y*b.y + b.z*b.z + b.w*b.w;
    short8 sv;
    sv[0]=(short)f2bf(a.x); sv[1]=(short)f2bf(a.y); sv[2]=(short)f2bf(a.z); sv[3]=(short)f2bf(a.w);
    sv[4]=(short)f2bf(b.x); sv[5]=(short)f2bf(b.y); sv[6]=(short)f2bf(b.z); sv[7]=(short)f2bf(b.w);
    reinterpret_cast<short8*>(embb2)[(size_t)(c * 8 + m) * 64 + l] = sv;

    // row norms: sum partials over q-groups (within wave), then over waves (LDS)
    s += __shfl_xor(s, 16, 64);
    s += __shfl_xor(s, 32, 64);
    if (l < 16) snormw[m][l] = s;
    __syncthreads();
    if (tid < 16) {
        float t = 0.f;
        #pragma unroll
        for (int mm = 0; mm < 8; ++mm) t += snormw[mm][tid];
        hneT[c * 16 + tid] = -0.5f * t;
    }
    if (c == 0 && tid == 0) *lossAcc = 0.f;
}

// ---- kernel 1: barrier-free, LDS-free MFMA scan; 4 indep acc chains ----
__launch_bounds__(THREADS, 2)
__global__ void k_main(const float* __restrict__ z,
                       const unsigned short* __restrict__ embb2,
                       const float* __restrict__ hneT,
                       const float* __restrict__ emb,
                       float* __restrict__ out,
                       float* __restrict__ lossAcc) {
    const int tid  = threadIdx.x;
    const int lane = tid & 63;
    const int w    = tid >> 6;            // 0..3
    const int r    = lane & 15;
    const int q    = lane >> 4;           // 0..3
    const long grow0 = (long)blockIdx.x * ROWS_PER_BLOCK + w * ROWS_PER_WAVE;

    // ---- A fragments (bf16, regs) + exact f32 row norms ----
    short8 af[2][8];
    float  zn[2];
    #pragma unroll
    for (int t = 0; t < 2; ++t) {
        const float* zr = z + (grow0 + t * 16 + r) * DIM + q * 8;
        float s = 0.f;
        #pragma unroll
        for (int m = 0; m < 8; ++m) {
            float4 a = *reinterpret_cast<const float4*>(zr + m * 32);
            float4 b = *reinterpret_cast<const float4*>(zr + m * 32 + 4);
            s += a.x*a.x + a.y*a.y + a.z*a.z + a.w*a.w
               + b.x*b.x + b.y*b.y + b.z*b.z + b.w*b.w;
            short8 sv;
            sv[0]=(short)f2bf(a.x); sv[1]=(short)f2bf(a.y); sv[2]=(short)f2bf(a.z); sv[3]=(short)f2bf(a.w);
            sv[4]=(short)f2bf(b.x); sv[5]=(short)f2bf(b.y); sv[6]=(short)f2bf(b.z); sv[7]=(short)f2bf(b.w);
            af[t][m] = sv;
        }
        s += __shfl_xor(s, 16, 64);
        s += __shfl_xor(s, 32, 64);
        zn[t] = s;                        // norm of row (t*16 + r), all lanes
    }

    float kb0[4], kb1[4];
    #pragma unroll
    for (int j = 0; j < 4; ++j) { kb0[j] = -1e30f; kb1[j] = -1e30f; }

    const char* ebase = reinterpret_cast<const char*>(embb2) + (size_t)lane * 16;

    // ---- 32 iters x (2 chunks x 16 codes); 4 independent MFMA chains ----
    for (int it = 0; it < 32; ++it) {
        const char* bp = ebase + (size_t)it * 16384;
        short8 bf[16];
        #pragma unroll
        for (int k = 0; k < 16; ++k)
            bf[k] = *reinterpret_cast<const short8*>(bp + k * 1024);

        const float hne0 = hneT[it * 32 + r];
        const float hne1 = hneT[it * 32 + 16 + r];
        f32x4 a00 = {hne0, hne0, hne0, hne0};   // tile0 x chunk0
        f32x4 a10 = {hne0, hne0, hne0, hne0};   // tile1 x chunk0
        f32x4 a01 = {hne1, hne1, hne1, hne1};   // tile0 x chunk1
        f32x4 a11 = {hne1, hne1, hne1, hne1};   // tile1 x chunk1
        #pragma unroll
        for (int m = 0; m < 8; ++m) {
            a00 = __builtin_amdgcn_mfma_f32_16x16x32_bf16(af[0][m], bf[m],     a00, 0, 0, 0);
            a10 = __builtin_amdgcn_mfma_f32_16x16x32_bf16(af[1][m], bf[m],     a10, 0, 0, 0);
            a01 = __builtin_amdgcn_mfma_f32_16x16x32_bf16(af[0][m], bf[m + 8], a01, 0, 0, 0);
            a11 = __builtin_amdgcn_mfma_f32_16x16x32_bf16(af[1][m], bf[m + 8], a11, 0, 0, 0);
        }

        // tagged-float running argmax of (z.e - ||e||^2/2); low 10 bits = 1023-code
        const unsigned tag0 = 1023u - (unsigned)(it * 32 + r);
        const unsigned tag1 = tag0 - 16u;
        #pragma unroll
        for (int j = 0; j < 4; ++j) {
            kb0[j] = fmaxf(kb0[j], __uint_as_float((__float_as_uint(a00[j]) & 0xFFFFFC00u) | tag0));
            kb0[j] = fmaxf(kb0[j], __uint_as_float((__float_as_uint(a01[j]) & 0xFFFFFC00u) | tag1));
            kb1[j] = fmaxf(kb1[j], __uint_as_float((__float_as_uint(a10[j]) & 0xFFFFFC00u) | tag0));
            kb1[j] = fmaxf(kb1[j], __uint_as_float((__float_as_uint(a11[j]) & 0xFFFFFC00u) | tag1));
        }
    }

    // ---- one-time cross-lane max over the 16 code-lanes ----
    #pragma unroll
    for (int j = 0; j < 4; ++j) {
        #pragma unroll
        for (int m = 1; m < 16; m <<= 1) {
            kb0[j] = fmaxf(kb0[j], __shfl_xor(kb0[j], m, 64));
            kb1[j] = fmaxf(kb1[j], __shfl_xor(kb1[j], m, 64));
        }
    }

    // ---- epilogue: per-row gather (1 KB coalesced per instr) + loss ----
    float lp = 0.f;
    #pragma unroll
    for (int rr = 0; rr < 32; ++rr) {
        const int t = rr >> 4, r16 = rr & 15;
        const int qq = r16 >> 2, rsub = r16 & 3;
        float kv = __shfl((t == 0) ? kb0[rsub] : kb1[rsub], qq * 16, 64);
        const unsigned ku = __float_as_uint(kv);
        const int   code  = 1023 - (int)(ku & 1023u);
        const float score = __uint_as_float(ku & 0xFFFFFC00u);   // dot - ||e||^2/2
        float4 v = *reinterpret_cast<const float4*>(emb + (size_t)code * DIM + lane * 4);
        *reinterpret_cast<float4*>(out + (size_t)(grow0 + rr) * DIM + lane * 4) = v;
        float zr = __shfl(zn[t], r16, 64);                        // ||z_row||^2
        lp += zr - 2.f * score;                                   // = ||z - e||^2
    }
    if (lane == 0) atomicAdd(lossAcc, lp);
}

// ---- kernel 2: finalize losses ----
__global__ void k_loss(const float* __restrict__ lossAcc, float* __restrict__ out2) {
    float loss = 0.5f * lossAcc[0] * (1.f / 16777216.f);   // 0.5 * mean over N*D
    out2[0] = loss;
    out2[1] = loss;
}

extern "C" void kernel_launch(void* const* d_in, const int* in_sizes, int n_in,
                              void* d_out, int out_size, void* d_ws, size_t ws_size,
                              hipStream_t stream) {
    const float* z   = (const float*)d_in[0];
    const float* emb = (const float*)d_in[1];
    float* out = (float*)d_out;
    char*  ws  = (char*)d_ws;
    float* lossAcc        = (float*)ws;                         // 4 B
    float* hneT           = (float*)(ws + 256);                 // 4 KB: -||e||^2/2
    unsigned short* embb2 = (unsigned short*)(ws + 256 + 4096); // 512 KB packed

    k_prep<<<K_CODES / 16, 512, 0, stream>>>(emb, embb2, hneT, lossAcc);
    k_main<<<NBLOCKS, THREADS, 0, stream>>>(z, embb2, hneT, emb, out, lossAcc);
    k_loss<<<1, 1, 0, stream>>>(lossAcc, out + (long)NROWS * DIM);
}

// Round 5
// 167.228 us; speedup vs baseline: 1.6536x; 1.1910x over previous
//
#include <hip/hip_runtime.h>

#define K_CODES 1024
#define DIM     256
#define NROWS   65536      // 64*32*32
#define THREADS 256        // 4 waves per block
#define ROWS_PER_WAVE 32
#define ROWS_PER_BLOCK 128
#define NBLOCKS (NROWS / ROWS_PER_BLOCK)   // 512
#define NCHUNK  64         // chunks of 16 codes

typedef __attribute__((ext_vector_type(8))) short short8;
typedef __attribute__((ext_vector_type(4))) float f32x4;

__device__ __forceinline__ unsigned short f2bf(float f) {
    unsigned int u = __float_as_uint(f);
    u += 0x7fffu + ((u >> 16) & 1u);          // round-to-nearest-even
    return (unsigned short)(u >> 16);
}

// ---- kernel 0: pack codebook into MFMA-B-fragment order + hne table ----
// embb2 record (c,m) lane l (16B): e[c*16 + (l&15)][m*32 + (l>>4)*8 + j], j=0..7
// -> k_main B-load is 64 lanes x 16B fully contiguous (1 KB/instr).
__global__ void k_prep(const float* __restrict__ emb,
                       unsigned short* __restrict__ embb2,
                       float* __restrict__ hneT,
                       float* __restrict__ lossAcc) {
    __shared__ float snormw[8][16];
    const int c   = blockIdx.x;        // chunk of 16 codes
    const int tid = threadIdx.x;
    const int m   = tid >> 6;          // fragment 0..7 (one wave each)
    const int l   = tid & 63;
    const int r   = l & 15;
    const int q   = l >> 4;

    const float* src = emb + (size_t)(c * 16 + r) * DIM + m * 32 + q * 8;
    float4 a = *reinterpret_cast<const float4*>(src);
    float4 b = *reinterpret_cast<const float4*>(src + 4);
    float s = a.x*a.x + a.y*a.y + a.z*a.z + a.w*a.w
            + b.x*b.x + b.y*b.y + b.z*b.z + b.w*b.w;
    short8 sv;
    sv[0]=(short)f2bf(a.x); sv[1]=(short)f2bf(a.y); sv[2]=(short)f2bf(a.z); sv[3]=(short)f2bf(a.w);
    sv[4]=(short)f2bf(b.x); sv[5]=(short)f2bf(b.y); sv[6]=(short)f2bf(b.z); sv[7]=(short)f2bf(b.w);
    reinterpret_cast<short8*>(embb2)[(size_t)(c * 8 + m) * 64 + l] = sv;

    s += __shfl_xor(s, 16, 64);
    s += __shfl_xor(s, 32, 64);
    if (l < 16) snormw[m][l] = s;
    __syncthreads();
    if (tid < 16) {
        float t = 0.f;
        #pragma unroll
        for (int mm = 0; mm < 8; ++mm) t += snormw[mm][tid];
        hneT[c * 16 + tid] = -0.5f * t;
    }
    if (c == 0 && tid == 0) *lossAcc = 0.f;
}

// ---- kernel 1: barrier-free MFMA scan, register-double-buffered B ----
__launch_bounds__(THREADS, 2)
__global__ void k_main(const float* __restrict__ z,
                       const unsigned short* __restrict__ embb2,
                       const float* __restrict__ hneT,
                       const float* __restrict__ emb,
                       float* __restrict__ out,
                       float* __restrict__ lossAcc) {
    const int tid  = threadIdx.x;
    const int lane = tid & 63;
    const int w    = tid >> 6;            // 0..3
    const int r    = lane & 15;
    const int q    = lane >> 4;           // 0..3
    const long grow0 = (long)blockIdx.x * ROWS_PER_BLOCK + w * ROWS_PER_WAVE;

    // ---- A fragments (bf16, regs) + exact f32 row norms ----
    short8 af[2][8];
    float  zn[2];
    #pragma unroll
    for (int t = 0; t < 2; ++t) {
        const float* zr = z + (grow0 + t * 16 + r) * DIM + q * 8;
        float s = 0.f;
        #pragma unroll
        for (int m = 0; m < 8; ++m) {
            float4 a = *reinterpret_cast<const float4*>(zr + m * 32);
            float4 b = *reinterpret_cast<const float4*>(zr + m * 32 + 4);
            s += a.x*a.x + a.y*a.y + a.z*a.z + a.w*a.w
               + b.x*b.x + b.y*b.y + b.z*b.z + b.w*b.w;
            short8 sv;
            sv[0]=(short)f2bf(a.x); sv[1]=(short)f2bf(a.y); sv[2]=(short)f2bf(a.z); sv[3]=(short)f2bf(a.w);
            sv[4]=(short)f2bf(b.x); sv[5]=(short)f2bf(b.y); sv[6]=(short)f2bf(b.z); sv[7]=(short)f2bf(b.w);
            af[t][m] = sv;
        }
        s += __shfl_xor(s, 16, 64);
        s += __shfl_xor(s, 32, 64);
        zn[t] = s;                        // norm of row (t*16 + r), all lanes
    }

    float kb0[4], kb1[4];
    #pragma unroll
    for (int j = 0; j < 4; ++j) { kb0[j] = -1e30f; kb1[j] = -1e30f; }

    const char* ebase = reinterpret_cast<const char*>(embb2) + (size_t)lane * 16;

    // chunk c, fragment m lives at byte (c*8+m)*1024 + lane*16
    auto loadc = [&](short8 (&buf)[8], int c) {
        const char* bp = ebase + (size_t)c * 8192;
        #pragma unroll
        for (int m = 0; m < 8; ++m)
            buf[m] = *reinterpret_cast<const short8*>(bp + m * 1024);
    };
    auto compute = [&](short8 (&buf)[8], int c) {
        const float hne = hneT[c * 16 + r];
        f32x4 a0 = {hne, hne, hne, hne};
        f32x4 a1 = {hne, hne, hne, hne};
        #pragma unroll
        for (int m = 0; m < 8; ++m) {
            a0 = __builtin_amdgcn_mfma_f32_16x16x32_bf16(af[0][m], buf[m], a0, 0, 0, 0);
            a1 = __builtin_amdgcn_mfma_f32_16x16x32_bf16(af[1][m], buf[m], a1, 0, 0, 0);
        }
        const unsigned tag = 1023u - (unsigned)(c * 16 + r);
        #pragma unroll
        for (int j = 0; j < 4; ++j) {
            kb0[j] = fmaxf(kb0[j], __uint_as_float((__float_as_uint(a0[j]) & 0xFFFFFC00u) | tag));
            kb1[j] = fmaxf(kb1[j], __uint_as_float((__float_as_uint(a1[j]) & 0xFFFFFC00u) | tag));
        }
    };

    // ---- software-pipelined scan: static double buffer, 2x unrolled ----
    short8 bufA[8], bufB[8];
    loadc(bufA, 0);
    for (int c = 0; c < NCHUNK; c += 2) {
        loadc(bufB, c + 1);
        compute(bufA, c);
        if (c + 2 < NCHUNK) loadc(bufA, c + 2);
        compute(bufB, c + 1);
    }

    // ---- one-time cross-lane max over the 16 code-lanes ----
    #pragma unroll
    for (int j = 0; j < 4; ++j) {
        #pragma unroll
        for (int m = 1; m < 16; m <<= 1) {
            kb0[j] = fmaxf(kb0[j], __shfl_xor(kb0[j], m, 64));
            kb1[j] = fmaxf(kb1[j], __shfl_xor(kb1[j], m, 64));
        }
    }

    // ---- epilogue: per-row gather (1 KB coalesced per instr) + loss ----
    float lp = 0.f;
    #pragma unroll
    for (int rr = 0; rr < 32; ++rr) {
        const int t = rr >> 4, r16 = rr & 15;
        const int qq = r16 >> 2, rsub = r16 & 3;
        float kv = __shfl((t == 0) ? kb0[rsub] : kb1[rsub], qq * 16, 64);
        const unsigned ku = __float_as_uint(kv);
        const int   code  = 1023 - (int)(ku & 1023u);
        const float score = __uint_as_float(ku & 0xFFFFFC00u);   // dot - ||e||^2/2
        float4 v = *reinterpret_cast<const float4*>(emb + (size_t)code * DIM + lane * 4);
        *reinterpret_cast<float4*>(out + (size_t)(grow0 + rr) * DIM + lane * 4) = v;
        float zr = __shfl(zn[t], r16, 64);                        // ||z_row||^2
        lp += zr - 2.f * score;                                   // = ||z - e||^2
    }
    if (lane == 0) atomicAdd(lossAcc, lp);
}

// ---- kernel 2: finalize losses ----
__global__ void k_loss(const float* __restrict__ lossAcc, float* __restrict__ out2) {
    float loss = 0.5f * lossAcc[0] * (1.f / 16777216.f);   // 0.5 * mean over N*D
    out2[0] = loss;
    out2[1] = loss;
}

extern "C" void kernel_launch(void* const* d_in, const int* in_sizes, int n_in,
                              void* d_out, int out_size, void* d_ws, size_t ws_size,
                              hipStream_t stream) {
    const float* z   = (const float*)d_in[0];
    const float* emb = (const float*)d_in[1];
    float* out = (float*)d_out;
    char*  ws  = (char*)d_ws;
    float* lossAcc        = (float*)ws;                         // 4 B
    float* hneT           = (float*)(ws + 256);                 // 4 KB: -||e||^2/2
    unsigned short* embb2 = (unsigned short*)(ws + 256 + 4096); // 512 KB packed

    k_prep<<<K_CODES / 16, 512, 0, stream>>>(emb, embb2, hneT, lossAcc);
    k_main<<<NBLOCKS, THREADS, 0, stream>>>(z, embb2, hneT, emb, out, lossAcc);
    k_loss<<<1, 1, 0, stream>>>(lossAcc, out + (long)NROWS * DIM);
}